// Round 10
// baseline (655.563 us; speedup 1.0000x reference)
//
#include <hip/hip_runtime.h>
#include <cfloat>
#include <cstdint>

// MahalanobisKnnModule v10: v8 pipeline + B-resident LDS (v9 insight, done right).
//   cross: B (128 cols x 256 k hi-bf16, 64 KB) staged to LDS ONCE per block;
//   A staged via global_load_lds (linear [oct][row] layout, no XOR needed),
//   double-buffered with counted vmcnt(4); barriers protect only the 16 KB
//   A tile. 1 block/CU (109 KB LDS), grid 512 = exactly 2 rounds.
//   Other kernels unchanged from v9 (all ref-verified absmax 0).

#define DD    256
#define NLAB  100
#define KNN   5
#define COLS  128
#define CHUNK 3200
#define NSRC  8

typedef float4 f4;
typedef __attribute__((ext_vector_type(8))) short bfrag;   // 8 bf16
typedef __attribute__((ext_vector_type(4))) float f32x4;

__device__ __forceinline__ void gload_lds16(const void* g, void* l) {
  __builtin_amdgcn_global_load_lds(
      (const __attribute__((address_space(1))) void*)g,
      (__attribute__((address_space(3))) void*)l, 16, 0, 0);
}

__device__ __forceinline__ uint32_t hi16(float v) {
  return ((__float_as_uint(v) + 0x8000u) & 0xffff0000u) >> 16;
}

__device__ __forceinline__ void split3(float v, uint32_t& h, uint32_t& m, uint32_t& l) {
  uint32_t b = __float_as_uint(v);
  uint32_t hb = (b + 0x8000u) & 0xffff0000u;
  float r1 = v - __uint_as_float(hb);
  uint32_t b1 = __float_as_uint(r1);
  uint32_t mb = (b1 + 0x8000u) & 0xffff0000u;
  float r2 = r1 - __uint_as_float(mb);
  uint32_t lb = (__float_as_uint(r2) + 0x8000u) & 0xffff0000u;
  h = hb >> 16; m = mb >> 16; l = lb >> 16;
}

__device__ __forceinline__ bool lex_lt(float v, int id, float rv, int rid) {
  return (v < rv) || (v == rv && id < rid);
}

__device__ __forceinline__ void ins5run(float (&bv)[KNN], int (&bi)[KNN], float v, int id) {
  if (v < bv[4]) {
    if (v < bv[3]) {
      bv[4] = bv[3]; bi[4] = bi[3];
      if (v < bv[2]) {
        bv[3] = bv[2]; bi[3] = bi[2];
        if (v < bv[1]) {
          bv[2] = bv[1]; bi[2] = bi[1];
          if (v < bv[0]) {
            bv[1] = bv[0]; bi[1] = bi[0]; bv[0] = v; bi[0] = id;
          } else { bv[1] = v; bi[1] = id; }
        } else { bv[2] = v; bi[2] = id; }
      } else { bv[3] = v; bi[3] = id; }
    } else { bv[4] = v; bi[4] = id; }
  }
}

__device__ __forceinline__ void ins5lex(float (&bv)[KNN], int (&bi)[KNN], float v, int id) {
  if (!lex_lt(v, id, bv[4], bi[4])) return;
  if (lex_lt(v, id, bv[3], bi[3])) {
    bv[4] = bv[3]; bi[4] = bi[3];
    if (lex_lt(v, id, bv[2], bi[2])) {
      bv[3] = bv[2]; bi[3] = bi[2];
      if (lex_lt(v, id, bv[1], bi[1])) {
        bv[2] = bv[1]; bi[2] = bi[1];
        if (lex_lt(v, id, bv[0], bi[0])) {
          bv[1] = bv[0]; bi[1] = bi[0]; bv[0] = v; bi[0] = id;
        } else { bv[1] = v; bi[1] = id; }
      } else { bv[2] = v; bi[2] = id; }
    } else { bv[3] = v; bi[3] = id; }
  } else { bv[4] = v; bi[4] = id; }
}

__device__ __forceinline__ void ins10(float (&bv)[10], int (&bi)[10], float v, int id) {
  if (!lex_lt(v, id, bv[9], bi[9])) return;
  bool placed = false;
#pragma unroll
  for (int s = 9; s >= 1; --s) {
    if (!placed) {
      if (lex_lt(v, id, bv[s - 1], bi[s - 1])) { bv[s] = bv[s - 1]; bi[s] = bi[s - 1]; }
      else { bv[s] = v; bi[s] = id; placed = true; }
    }
  }
  if (!placed) { bv[0] = v; bi[0] = id; }
}

// ---------- msplit: MT3 = 3-split of M, frag order for xprod ----------
__global__ __launch_bounds__(256)
void msplit_kernel(const float* __restrict__ M, uint4* __restrict__ MT3) {
  int id = blockIdx.x * 256 + threadIdx.x;
  int lane = id & 63;
  int nf = (id >> 6) & 15;
  int kit = id >> 10;
  int d = nf * 16 + (lane & 15);
  int kb = kit * 32 + (lane >> 4) * 8;
  uint32_t hw[4], mw[4], lw[4];
#pragma unroll
  for (int e = 0; e < 4; ++e) {
    uint32_t h0, m0, l0, h1, m1, l1;
    split3(M[(size_t)(kb + 2 * e) * DD + d], h0, m0, l0);
    split3(M[(size_t)(kb + 2 * e + 1) * DD + d], h1, m1, l1);
    hw[e] = h0 | (h1 << 16); mw[e] = m0 | (m1 << 16); lw[e] = l0 | (l1 << 16);
  }
  size_t base = (size_t)(kit * 16 + nf) * 3 * 64;
  MT3[base + lane]       = make_uint4(hw[0], hw[1], hw[2], hw[3]);
  MT3[base + 64 + lane]  = make_uint4(mw[0], mw[1], mw[2], mw[3]);
  MT3[base + 128 + lane] = make_uint4(lw[0], lw[1], lw[2], lw[3]);
}

// ---------- xsplit: Xsp[(tile*4+kit)*8+oct][row] = hi bf16 of X ----------
__global__ __launch_bounds__(256)
void xsplit_kernel(const float* __restrict__ X, uint4* __restrict__ Xsp, int NT) {
  __shared__ float lds[128 * 65];
  const int bid = blockIdx.x;             // tile*4 + kit
  const int tile = bid >> 2, kit = bid & 3;
  const int t = threadIdx.x;
#pragma unroll
  for (int i = 0; i < 8; ++i) {
    int idx = i * 256 + t;                // f4 slot in [128 rows][16 f4]
    int row = idx >> 4, c4 = idx & 15;
    int grow = tile * 128 + row; if (grow >= NT) grow = NT - 1;
    f4 v = *(const f4*)(X + (size_t)grow * DD + kit * 64 + c4 * 4);
    float* p = &lds[row * 65 + c4 * 4];
    p[0] = v.x; p[1] = v.y; p[2] = v.z; p[3] = v.w;
  }
  __syncthreads();
#pragma unroll
  for (int i = 0; i < 4; ++i) {
    int slot = i * 256 + t;               // [oct(8)][row(128)]
    int m = slot & 127, oct = slot >> 7;
    const float* p = &lds[m * 65 + oct * 8];
    uint32_t h0 = hi16(p[0]) | (hi16(p[1]) << 16);
    uint32_t h1 = hi16(p[2]) | (hi16(p[3]) << 16);
    uint32_t h2 = hi16(p[4]) | (hi16(p[5]) << 16);
    uint32_t h3 = hi16(p[6]) | (hi16(p[7]) << 16);
    Xsp[((size_t)bid << 10) + slot] = make_uint4(h0, h1, h2, h3);
  }
}

// ---------- prep: ZTf32 + Z2h[ct][cc*32 + (oct^(cc&7))] = hi bf16 of -2*ZT^T ----------
__global__ __launch_bounds__(256)
void prep_kernel(const float* __restrict__ M, const float* __restrict__ Xe,
                 float* __restrict__ ZTf32, uint4* __restrict__ Z2h, int NEVAL) {
  __shared__ float xe_lds[64 * 257];
  const int t = threadIdx.x;
  const int j0 = blockIdx.x * 64;
  const int part = t >> 6;
  const int dbase = blockIdx.y * 64 + part * 16;
#pragma unroll
  for (int it = 0; it < 16; ++it) {
    int id = t + it * 256;
    int r = id >> 6, k4 = id & 63;
    f4 v = *(const f4*)(Xe + (size_t)(j0 + r) * DD + 4 * k4);
    float* p = &xe_lds[r * 257 + 4 * k4];
    p[0] = v.x; p[1] = v.y; p[2] = v.z; p[3] = v.w;
  }
  __syncthreads();
  const int j = t & 63;
  float acc[16];
#pragma unroll
  for (int dd = 0; dd < 16; ++dd) acc[dd] = 0.f;
  for (int k4 = 0; k4 < 64; ++k4) {
    const float* xp = &xe_lds[j * 257 + 4 * k4];
    float x0 = xp[0], x1 = xp[1], x2 = xp[2], x3 = xp[3];
#pragma unroll
    for (int dd = 0; dd < 16; ++dd) {
      f4 m = *(const f4*)(M + (size_t)(dbase + dd) * DD + 4 * k4);
      acc[dd] = fmaf(m.x, x0, fmaf(m.y, x1, fmaf(m.z, x2, fmaf(m.w, x3, acc[dd]))));
    }
  }
  const int jg = j0 + j;
#pragma unroll
  for (int dd = 0; dd < 16; ++dd)
    ZTf32[(size_t)(dbase + dd) * NEVAL + jg] = acc[dd];
  const int cc = jg & 127, ct2 = jg >> 7;
  const int obase = dbase >> 3;            // global k-oct base (2 octs/thread)
#pragma unroll
  for (int u = 0; u < 2; ++u) {
    int oct = obase + u;
    uint32_t hw[4];
#pragma unroll
    for (int e = 0; e < 4; ++e) {
      uint32_t a0 = hi16(-2.f * acc[u * 8 + 2 * e]);
      uint32_t a1 = hi16(-2.f * acc[u * 8 + 2 * e + 1]);
      hw[e] = a0 | (a1 << 16);
    }
    Z2h[(size_t)ct2 * 4096 + cc * 32 + (oct ^ (cc & 7))] =
        make_uint4(hw[0], hw[1], hw[2], hw[3]);
  }
}

// ---------- xprod: 3-split MFMA GEMM + fused row-dot (unchanged) ----------
__global__ __launch_bounds__(256, 2)
void xprod_kernel(const float* __restrict__ X, const uint4* __restrict__ MT3,
                  float* __restrict__ Xprod, int NT) {
  __shared__ __align__(16) char pool[66560];
  short* A3 = (short*)pool;
  char*  B3 = pool + 12288;
  float* C  = (float*)pool;

  const int t = threadIdx.x;
  const int w = t >> 6, lane = t & 63;
  const int l15 = lane & 15, l4 = lane >> 4;
  const int row0 = blockIdx.x * 64;
  const int r = t >> 2, g = t & 3;
  int grow = row0 + r; if (grow >= NT) grow = NT - 1;
  const float* xrow = X + (size_t)grow * DD;

  f32x4 acc[16];
#pragma unroll
  for (int nf = 0; nf < 16; ++nf) { f32x4 z = {0.f, 0.f, 0.f, 0.f}; acc[nf] = z; }

  for (int kit = 0; kit < 8; ++kit) {
    f4 v0 = *(const f4*)(xrow + kit * 32 + g * 8);
    f4 v1 = *(const f4*)(xrow + kit * 32 + g * 8 + 4);
    uint32_t h[8], m[8], l[8];
    split3(v0.x, h[0], m[0], l[0]); split3(v0.y, h[1], m[1], l[1]);
    split3(v0.z, h[2], m[2], l[2]); split3(v0.w, h[3], m[3], l[3]);
    split3(v1.x, h[4], m[4], l[4]); split3(v1.y, h[5], m[5], l[5]);
    split3(v1.z, h[6], m[6], l[6]); split3(v1.w, h[7], m[7], l[7]);
    int slot = (r & 15) + 16 * g;
    int wb = r >> 4;
    *(uint4*)((char*)A3 + ((wb * 3 + 0) * 64 + slot) * 16) =
        make_uint4(h[0] | (h[1] << 16), h[2] | (h[3] << 16), h[4] | (h[5] << 16), h[6] | (h[7] << 16));
    *(uint4*)((char*)A3 + ((wb * 3 + 1) * 64 + slot) * 16) =
        make_uint4(m[0] | (m[1] << 16), m[2] | (m[3] << 16), m[4] | (m[5] << 16), m[6] | (m[7] << 16));
    *(uint4*)((char*)A3 + ((wb * 3 + 2) * 64 + slot) * 16) =
        make_uint4(l[0] | (l[1] << 16), l[2] | (l[3] << 16), l[4] | (l[5] << 16), l[6] | (l[7] << 16));
    const uint4* src = MT3 + (size_t)kit * 3072;
#pragma unroll
    for (int i = 0; i < 12; ++i) {
      int gs = (w * 12 + i) * 64;
      gload_lds16(src + gs + lane, B3 + (size_t)gs * 16);
    }
    __syncthreads();
    bfrag ah = *(const bfrag*)((const char*)A3 + ((w * 3 + 0) * 64 + lane) * 16);
    bfrag am = *(const bfrag*)((const char*)A3 + ((w * 3 + 1) * 64 + lane) * 16);
    bfrag al = *(const bfrag*)((const char*)A3 + ((w * 3 + 2) * 64 + lane) * 16);
#pragma unroll
    for (int nf = 0; nf < 16; ++nf) {
      bfrag bh = *(const bfrag*)(B3 + ((nf * 3 + 0) * 64 + lane) * 16);
      bfrag bm = *(const bfrag*)(B3 + ((nf * 3 + 1) * 64 + lane) * 16);
      bfrag bl = *(const bfrag*)(B3 + ((nf * 3 + 2) * 64 + lane) * 16);
      acc[nf] = __builtin_amdgcn_mfma_f32_16x16x32_bf16(ah, bh, acc[nf], 0, 0, 0);
      acc[nf] = __builtin_amdgcn_mfma_f32_16x16x32_bf16(ah, bm, acc[nf], 0, 0, 0);
      acc[nf] = __builtin_amdgcn_mfma_f32_16x16x32_bf16(am, bh, acc[nf], 0, 0, 0);
      acc[nf] = __builtin_amdgcn_mfma_f32_16x16x32_bf16(ah, bl, acc[nf], 0, 0, 0);
      acc[nf] = __builtin_amdgcn_mfma_f32_16x16x32_bf16(al, bh, acc[nf], 0, 0, 0);
      acc[nf] = __builtin_amdgcn_mfma_f32_16x16x32_bf16(am, bm, acc[nf], 0, 0, 0);
    }
    __syncthreads();
  }
#pragma unroll
  for (int nf = 0; nf < 16; ++nf)
#pragma unroll
    for (int reg = 0; reg < 4; ++reg)
      C[(size_t)(16 * w + l4 * 4 + reg) * 260 + nf * 16 + l15] = acc[nf][reg];
  __syncthreads();
  float part = 0.f;
#pragma unroll
  for (int j = 0; j < 16; ++j) {
    f4 xv = *(const f4*)(xrow + g * 64 + 4 * j);
    f4 cv = *(const f4*)&C[(size_t)r * 260 + g * 64 + 4 * j];
    part = fmaf(xv.x, cv.x, fmaf(xv.y, cv.y, fmaf(xv.z, cv.z, fmaf(xv.w, cv.w, part))));
  }
  part += __shfl_xor(part, 1);
  part += __shfl_xor(part, 2);
  if (g == 0 && row0 + r < NT) Xprod[row0 + r] = part;
}

// ------- cross v10: B-resident LDS, A gload_lds dbuf, counted vmcnt(4) -------
__global__ __launch_bounds__(256, 1)
void cross_topk_kernel(const uint4* __restrict__ Xsp, const uint4* __restrict__ Z2h,
                       const float* __restrict__ Xprod,
                       float* __restrict__ cand_v, int* __restrict__ cand_i,
                       int NT, int NCH) {
  __shared__ __align__(16) char B_lds[65536];     // [cc][32 xor-swizzled uint4]
  __shared__ __align__(16) char Abuf[2][16384];   // [oct8][row128] uint4, linear
  __shared__ __align__(16) float xp_lds[3328];

  const int t = threadIdx.x;
  const int w = t >> 6, lane = t & 63;
  const int l15 = lane & 15, l4 = lane >> 4;
  const int wr = (w & 1) * 64;         // wave row offset
  const int wc = (w >> 1) * 64;        // wave col offset
  // XCD-aware swizzle: same-chunk col-tiles share an XCD's L2
  int n = blockIdx.y * gridDim.x + blockIdx.x;
  int nwg = gridDim.x * gridDim.y;
  int wg = n;
  if ((nwg & 7) == 0) wg = (n & 7) * (nwg >> 3) + (n >> 3);
  const int ct = wg % gridDim.x;
  const int ch = wg / gridDim.x;
  const int c0 = ct * COLS;
  const int row0 = ch * CHUNK;
  const int rows = min(CHUNK, NT - row0);
  const int nrp = (rows + 127) >> 7;
  const int G = nrp * 4;
  const int tile0 = ch * (CHUNK >> 7);

  float bv[4][KNN]; int bi[4][KNN];
#pragma unroll
  for (int nf = 0; nf < 4; ++nf)
#pragma unroll
    for (int s = 0; s < KNN; ++s) { bv[nf][s] = FLT_MAX; bi[nf][s] = 0x7fffffff; }

  f32x4 acc[4][4];
#pragma unroll
  for (int mf = 0; mf < 4; ++mf)
#pragma unroll
    for (int nf = 0; nf < 4; ++nf) { f32x4 z = {0.f, 0.f, 0.f, 0.f}; acc[mf][nf] = z; }

  auto stageA = [&](int gg) {          // one kit64 A tile (1024 uint4), linear
    const uint4* src = Xsp + (((size_t)(tile0 + (gg >> 2)) * 4 + (gg & 3)) << 10);
    char* dst = Abuf[gg & 1];
#pragma unroll
    for (int i = 0; i < 4; ++i) {
      int sb = (w * 4 + i) * 64;
      gload_lds16(src + sb + lane, dst + sb * 16);
    }
  };

  // ---- prologue: B (once) + Xprod chunk + A0; full drain, one barrier ----
  const uint4* zsrc = Z2h + (size_t)ct * 4096;
#pragma unroll
  for (int i = 0; i < 16; ++i) {
    int slot = i * 256 + t;
    gload_lds16(zsrc + slot, B_lds + (size_t)slot * 16);
  }
  const uint4* xpsrc = (const uint4*)(Xprod + row0);
#pragma unroll
  for (int i = 0; i < 4; ++i) {
    int rr = w * 4 + i;                // wave-uniform guard
    if (rr < 13) {
      int sb = rr * 64;
      gload_lds16(xpsrc + sb + lane, (char*)xp_lds + sb * 16);
    }
  }
  stageA(0);
  asm volatile("s_waitcnt vmcnt(0)" ::: "memory");
  __builtin_amdgcn_s_barrier();

  for (int rp = 0; rp < nrp; ++rp) {
#pragma unroll
    for (int kit = 0; kit < 4; ++kit) {
      const int g = rp * 4 + kit;
      if (g < G - 1) {
        stageA(g + 1);
        asm volatile("s_waitcnt vmcnt(4)" ::: "memory");
      } else {
        asm volatile("s_waitcnt vmcnt(0)" ::: "memory");
      }
      __builtin_amdgcn_s_barrier();
      // A frags: linear layout, base + immediate offsets, no XOR
      const char* Ab = Abuf[kit & 1] + l4 * 2048 + (wr + l15) * 16;
      bfrag ah[4][2], bh[4][2];
#pragma unroll
      for (int mf = 0; mf < 4; ++mf)
#pragma unroll
        for (int ks = 0; ks < 2; ++ks)
          ah[mf][ks] = *(const bfrag*)(Ab + ks * 8192 + mf * 256);
      // B frags: resident, XOR-swizzled rows
#pragma unroll
      for (int nf = 0; nf < 4; ++nf) {
        int cc = wc + nf * 16 + l15;
        const char* rb = B_lds + cc * 512;
#pragma unroll
        for (int ks = 0; ks < 2; ++ks)
          bh[nf][ks] = *(const bfrag*)(rb + (((kit * 8 + ks * 4 + l4) ^ (cc & 7)) << 4));
      }
      __builtin_amdgcn_s_setprio(1);
#pragma unroll
      for (int ks = 0; ks < 2; ++ks)
#pragma unroll
        for (int mf = 0; mf < 4; ++mf)
#pragma unroll
          for (int nf = 0; nf < 4; ++nf)
            acc[mf][nf] = __builtin_amdgcn_mfma_f32_16x16x32_bf16(
                ah[mf][ks], bh[nf][ks], acc[mf][nf], 0, 0, 0);
      __builtin_amdgcn_s_setprio(0);
      if (kit == 3) {
        const int trow0 = row0 + rp * 128;
        const bool full = (trow0 + 128 <= NT);
#pragma unroll
        for (int mf = 0; mf < 4; ++mf) {
          f4 xv = *(const f4*)&xp_lds[rp * 128 + wr + mf * 16 + l4 * 4];
          const int rbase = trow0 + wr + mf * 16 + l4 * 4;
#pragma unroll
          for (int nf = 0; nf < 4; ++nf) {
            float v0 = xv.x + acc[mf][nf][0];
            float v1 = xv.y + acc[mf][nf][1];
            float v2 = xv.z + acc[mf][nf][2];
            float v3 = xv.w + acc[mf][nf][3];
            if (!full) {
              if (rbase + 0 >= NT) v0 = FLT_MAX;
              if (rbase + 1 >= NT) v1 = FLT_MAX;
              if (rbase + 2 >= NT) v2 = FLT_MAX;
              if (rbase + 3 >= NT) v3 = FLT_MAX;
            }
            float mn = fminf(fminf(v0, v1), fminf(v2, v3));
            if (mn < bv[nf][4]) {        // rare path: detailed insert
              ins5run(bv[nf], bi[nf], v0, rbase);
              ins5run(bv[nf], bi[nf], v1, rbase + 1);
              ins5run(bv[nf], bi[nf], v2, rbase + 2);
              ins5run(bv[nf], bi[nf], v3, rbase + 3);
            }
            f32x4 zz = {0.f, 0.f, 0.f, 0.f};
            acc[mf][nf] = zz;
          }
        }
      }
      __builtin_amdgcn_s_barrier();
    }
  }

  // write 8 partial lists per column, layout [col][ch][src][5]
#pragma unroll
  for (int nf = 0; nf < 4; ++nf) {
    int col = c0 + wc + nf * 16 + l15;
    size_t o = ((size_t)col * NCH + ch) * (NSRC * KNN) + ((w & 1) * 4 + l4) * KNN;
#pragma unroll
    for (int s = 0; s < KNN; ++s) { cand_v[o + s] = bv[nf][s]; cand_i[o + s] = bi[nf][s]; }
  }
}

// ------------- finalize: merge 1280 -> top-10 -> exact rescore -> top-5 -------------
__global__ __launch_bounds__(64)
void finalize_kernel(const float* __restrict__ cand_v, const int* __restrict__ cand_i,
                     const float* __restrict__ X, const float* __restrict__ ZTf32,
                     const float* __restrict__ Xprod, const int* __restrict__ y,
                     float* __restrict__ out, int NCH, int NEVAL, int NT) {
  __shared__ float ztl[DD];
  const int j = blockIdx.x;
  const int lane = threadIdx.x;
#pragma unroll
  for (int i = 0; i < 4; ++i) {
    int k = lane + 64 * i;
    ztl[k] = ZTf32[(size_t)k * NEVAL + j];
  }
  __syncthreads();

  float bv[10]; int bi[10];
#pragma unroll
  for (int s = 0; s < 10; ++s) { bv[s] = FLT_MAX; bi[s] = 0x7fffffff; }
  const int NC = NCH * NSRC * KNN;     // 1280, contiguous per column
  const float* cvj = cand_v + (size_t)j * NC;
  const int*   cij = cand_i + (size_t)j * NC;
  for (int p = lane; p < NC; p += 64)
    ins10(bv, bi, cvj[p], cij[p]);
#pragma unroll
  for (int st = 0; st < 6; ++st) {
    float pv[10]; int pi[10];
#pragma unroll
    for (int s = 0; s < 10; ++s) {
      pv[s] = __shfl_xor(bv[s], 1 << st);
      pi[s] = __shfl_xor(bi[s], 1 << st);
    }
#pragma unroll
    for (int s = 0; s < 10; ++s) ins10(bv, bi, pv[s], pi[s]);
  }
  float ex[10];
#pragma unroll
  for (int c = 0; c < 10; ++c) {
    int idx = bi[c];
    float part = 0.f;
#pragma unroll
    for (int i = 0; i < 4; ++i) {
      int k = lane + 64 * i;
      part = fmaf(X[(size_t)idx * DD + k], ztl[k], part);
    }
#pragma unroll
    for (int st = 0; st < 6; ++st) part += __shfl_xor(part, 1 << st);
    ex[c] = Xprod[idx] - 2.f * part;
  }
  float fv[KNN]; int fi[KNN];
#pragma unroll
  for (int s = 0; s < KNN; ++s) { fv[s] = FLT_MAX; fi[s] = 0x7fffffff; }
#pragma unroll
  for (int c = 0; c < 10; ++c) ins5lex(fv, fi, ex[c], bi[c]);
  int lb[KNN];
#pragma unroll
  for (int s = 0; s < KNN; ++s) lb[s] = y[fi[s]];
  for (int q = lane; q < NLAB; q += 64) {
    int cnt = (lb[0] == q) + (lb[1] == q) + (lb[2] == q) + (lb[3] == q) + (lb[4] == q);
    out[(size_t)j * NLAB + q] = (float)cnt - (float)q * 0.01f;
  }
}

extern "C" void kernel_launch(void* const* d_in, const int* in_sizes, int n_in,
                              void* d_out, int out_size, void* d_ws, size_t ws_size,
                              hipStream_t stream) {
  const float* X  = (const float*)d_in[0];
  const float* M  = (const float*)d_in[1];
  const float* Xe = (const float*)d_in[2];
  const int*   y  = (const int*)d_in[3];
  const int NT    = in_sizes[0] / DD;          // 100000
  const int NEVAL = in_sizes[2] / DD;          // 2048
  const int NCH   = (NT + CHUNK - 1) / CHUNK;  // 32
  const int NT64  = (NT + 63) / 64;
  const int NT128 = (NT + 127) / 128;          // 782

  char* ws = (char*)d_ws;
  uint4* Z2h    = (uint4*)ws;                               // 1 MB
  float* ZTf32  = (float*)(ws + (1 << 20));                 // 2 MB
  uint4* MT3    = (uint4*)(ws + (3 << 20));                 // 384 KB
  float* Xprod  = (float*)(ws + (3 << 20) + (448 << 10));   // NCH*CHUNK + pad
  float* cand_v = (float*)(ws + (4 << 20));                 // 10.5 MB
  int*   cand_i = (int*)(cand_v + (size_t)NEVAL * NCH * NSRC * KNN);
  uint4* Xsp    = (uint4*)(ws + (40ULL << 20));             // 51.2 MB
  float* out    = (float*)d_out;

  msplit_kernel<<<dim3(32), 256, 0, stream>>>(M, MT3);
  prep_kernel<<<dim3(NEVAL / 64, DD / 64), 256, 0, stream>>>(M, Xe, ZTf32, Z2h, NEVAL);
  xsplit_kernel<<<dim3(NT128 * 4), 256, 0, stream>>>(X, Xsp, NT);
  xprod_kernel<<<dim3(NT64), 256, 0, stream>>>(X, MT3, Xprod, NT);
  cross_topk_kernel<<<dim3(NEVAL / COLS, NCH), 256, 0, stream>>>(
      Xsp, Z2h, Xprod, cand_v, cand_i, NT, NCH);
  finalize_kernel<<<dim3(NEVAL), 64, 0, stream>>>(
      cand_v, cand_i, X, ZTf32, Xprod, y, out, NCH, NEVAL, NT);
}

// Round 11
// 520.957 us; speedup vs baseline: 1.2584x; 1.2584x over previous
//
#include <hip/hip_runtime.h>
#include <cfloat>
#include <cstdint>

// MahalanobisKnnModule v11: v8 pipeline at KS=32 with 3 blocks/CU.
//   R10 lessons: (a) A-layout MUST keep the XOR swizzle (bank conflicts),
//   (b) occupancy is the binding constraint -> shrink LDS, not traffic.
//   cross: 128x128 block tile, KS=32 phases (A/B dbuf 8KB each), counted
//   vmcnt(4), quad-XOR 64B-row layout, CHUNK=2176 -> grid 736 = one round
//   at 3 blocks/CU (41.5 KB LDS).
//   Other kernels: msplit/xprod/finalize unchanged (ref-verified absmax 0);
//   prep/xsplit re-indexed for the [kit32][512-slot] quad-XOR layout.

#define DD    256
#define NLAB  100
#define KNN   5
#define COLS  128
#define CHUNK 2176
#define NSRC  8

typedef float4 f4;
typedef __attribute__((ext_vector_type(8))) short bfrag;   // 8 bf16
typedef __attribute__((ext_vector_type(4))) float f32x4;

__device__ __forceinline__ void gload_lds16(const void* g, void* l) {
  __builtin_amdgcn_global_load_lds(
      (const __attribute__((address_space(1))) void*)g,
      (__attribute__((address_space(3))) void*)l, 16, 0, 0);
}

__device__ __forceinline__ uint32_t hi16(float v) {
  return ((__float_as_uint(v) + 0x8000u) & 0xffff0000u) >> 16;
}

__device__ __forceinline__ void split3(float v, uint32_t& h, uint32_t& m, uint32_t& l) {
  uint32_t b = __float_as_uint(v);
  uint32_t hb = (b + 0x8000u) & 0xffff0000u;
  float r1 = v - __uint_as_float(hb);
  uint32_t b1 = __float_as_uint(r1);
  uint32_t mb = (b1 + 0x8000u) & 0xffff0000u;
  float r2 = r1 - __uint_as_float(mb);
  uint32_t lb = (__float_as_uint(r2) + 0x8000u) & 0xffff0000u;
  h = hb >> 16; m = mb >> 16; l = lb >> 16;
}

__device__ __forceinline__ bool lex_lt(float v, int id, float rv, int rid) {
  return (v < rv) || (v == rv && id < rid);
}

__device__ __forceinline__ void ins5run(float (&bv)[KNN], int (&bi)[KNN], float v, int id) {
  if (v < bv[4]) {
    if (v < bv[3]) {
      bv[4] = bv[3]; bi[4] = bi[3];
      if (v < bv[2]) {
        bv[3] = bv[2]; bi[3] = bi[2];
        if (v < bv[1]) {
          bv[2] = bv[1]; bi[2] = bi[1];
          if (v < bv[0]) {
            bv[1] = bv[0]; bi[1] = bi[0]; bv[0] = v; bi[0] = id;
          } else { bv[1] = v; bi[1] = id; }
        } else { bv[2] = v; bi[2] = id; }
      } else { bv[3] = v; bi[3] = id; }
    } else { bv[4] = v; bi[4] = id; }
  }
}

__device__ __forceinline__ void ins5lex(float (&bv)[KNN], int (&bi)[KNN], float v, int id) {
  if (!lex_lt(v, id, bv[4], bi[4])) return;
  if (lex_lt(v, id, bv[3], bi[3])) {
    bv[4] = bv[3]; bi[4] = bi[3];
    if (lex_lt(v, id, bv[2], bi[2])) {
      bv[3] = bv[2]; bi[3] = bi[2];
      if (lex_lt(v, id, bv[1], bi[1])) {
        bv[2] = bv[1]; bi[2] = bi[1];
        if (lex_lt(v, id, bv[0], bi[0])) {
          bv[1] = bv[0]; bi[1] = bi[0]; bv[0] = v; bi[0] = id;
        } else { bv[1] = v; bi[1] = id; }
      } else { bv[2] = v; bi[2] = id; }
    } else { bv[3] = v; bi[3] = id; }
  } else { bv[4] = v; bi[4] = id; }
}

__device__ __forceinline__ void ins10(float (&bv)[10], int (&bi)[10], float v, int id) {
  if (!lex_lt(v, id, bv[9], bi[9])) return;
  bool placed = false;
#pragma unroll
  for (int s = 9; s >= 1; --s) {
    if (!placed) {
      if (lex_lt(v, id, bv[s - 1], bi[s - 1])) { bv[s] = bv[s - 1]; bi[s] = bi[s - 1]; }
      else { bv[s] = v; bi[s] = id; placed = true; }
    }
  }
  if (!placed) { bv[0] = v; bi[0] = id; }
}

// ---------- msplit: MT3 = 3-split of M, frag order for xprod ----------
__global__ __launch_bounds__(256)
void msplit_kernel(const float* __restrict__ M, uint4* __restrict__ MT3) {
  int id = blockIdx.x * 256 + threadIdx.x;
  int lane = id & 63;
  int nf = (id >> 6) & 15;
  int kit = id >> 10;
  int d = nf * 16 + (lane & 15);
  int kb = kit * 32 + (lane >> 4) * 8;
  uint32_t hw[4], mw[4], lw[4];
#pragma unroll
  for (int e = 0; e < 4; ++e) {
    uint32_t h0, m0, l0, h1, m1, l1;
    split3(M[(size_t)(kb + 2 * e) * DD + d], h0, m0, l0);
    split3(M[(size_t)(kb + 2 * e + 1) * DD + d], h1, m1, l1);
    hw[e] = h0 | (h1 << 16); mw[e] = m0 | (m1 << 16); lw[e] = l0 | (l1 << 16);
  }
  size_t base = (size_t)(kit * 16 + nf) * 3 * 64;
  MT3[base + lane]       = make_uint4(hw[0], hw[1], hw[2], hw[3]);
  MT3[base + 64 + lane]  = make_uint4(mw[0], mw[1], mw[2], mw[3]);
  MT3[base + 128 + lane] = make_uint4(lw[0], lw[1], lw[2], lw[3]);
}

// ---------- xsplit: Xsp[tile128][kit32 0..7][512 slots], quad-XOR ----------
// slot s: row m = s>>2, qs = s&3, k-oct q = qs ^ (m&3); holds hi bf16 of
// X[row][kit32*32 + q*8 .. +7]. Row stride 64B.
__global__ __launch_bounds__(256)
void xsplit_kernel(const float* __restrict__ X, uint4* __restrict__ Xsp,
                   int NT, int NTOT) {
  int id = blockIdx.x * 256 + threadIdx.x;
  if (id >= NTOT) return;
  int tile = id >> 12;
  int rem = id & 4095;
  int kit32 = rem >> 9;
  int s = rem & 511;
  int m = s >> 2, qs = s & 3;
  int q = qs ^ (m & 3);
  int row = tile * 128 + m; if (row >= NT) row = NT - 1;
  const float* src = X + (size_t)row * DD + kit32 * 32 + q * 8;
  f4 v0 = *(const f4*)src;
  f4 v1 = *(const f4*)(src + 4);
  uint32_t h0 = hi16(v0.x) | (hi16(v0.y) << 16);
  uint32_t h1 = hi16(v0.z) | (hi16(v0.w) << 16);
  uint32_t h2 = hi16(v1.x) | (hi16(v1.y) << 16);
  uint32_t h3 = hi16(v1.z) | (hi16(v1.w) << 16);
  Xsp[id] = make_uint4(h0, h1, h2, h3);
}

// ---------- prep: ZTf32 + Z2h[ct][kit32][cc*4 + (oq^(cc&3))] ----------
__global__ __launch_bounds__(256)
void prep_kernel(const float* __restrict__ M, const float* __restrict__ Xe,
                 float* __restrict__ ZTf32, uint4* __restrict__ Z2h, int NEVAL) {
  __shared__ float xe_lds[64 * 257];
  const int t = threadIdx.x;
  const int j0 = blockIdx.x * 64;
  const int part = t >> 6;
  const int dbase = blockIdx.y * 64 + part * 16;
#pragma unroll
  for (int it = 0; it < 16; ++it) {
    int id = t + it * 256;
    int r = id >> 6, k4 = id & 63;
    f4 v = *(const f4*)(Xe + (size_t)(j0 + r) * DD + 4 * k4);
    float* p = &xe_lds[r * 257 + 4 * k4];
    p[0] = v.x; p[1] = v.y; p[2] = v.z; p[3] = v.w;
  }
  __syncthreads();
  const int j = t & 63;
  float acc[16];
#pragma unroll
  for (int dd = 0; dd < 16; ++dd) acc[dd] = 0.f;
  for (int k4 = 0; k4 < 64; ++k4) {
    const float* xp = &xe_lds[j * 257 + 4 * k4];
    float x0 = xp[0], x1 = xp[1], x2 = xp[2], x3 = xp[3];
#pragma unroll
    for (int dd = 0; dd < 16; ++dd) {
      f4 m = *(const f4*)(M + (size_t)(dbase + dd) * DD + 4 * k4);
      acc[dd] = fmaf(m.x, x0, fmaf(m.y, x1, fmaf(m.z, x2, fmaf(m.w, x3, acc[dd]))));
    }
  }
  const int jg = j0 + j;
#pragma unroll
  for (int dd = 0; dd < 16; ++dd)
    ZTf32[(size_t)(dbase + dd) * NEVAL + jg] = acc[dd];
  const int cc = jg & 127, ct2 = jg >> 7;
  const int kit32 = dbase >> 5;
  const int oq = (dbase & 31) >> 3;        // 0 or 2
#pragma unroll
  for (int u = 0; u < 2; ++u) {
    uint32_t hw[4];
#pragma unroll
    for (int e = 0; e < 4; ++e) {
      uint32_t a0 = hi16(-2.f * acc[u * 8 + 2 * e]);
      uint32_t a1 = hi16(-2.f * acc[u * 8 + 2 * e + 1]);
      hw[e] = a0 | (a1 << 16);
    }
    int slot = cc * 4 + ((oq + u) ^ (cc & 3));
    Z2h[(size_t)ct2 * 4096 + kit32 * 512 + slot] =
        make_uint4(hw[0], hw[1], hw[2], hw[3]);
  }
}

// ---------- xprod: 3-split MFMA GEMM + fused row-dot (unchanged) ----------
__global__ __launch_bounds__(256, 2)
void xprod_kernel(const float* __restrict__ X, const uint4* __restrict__ MT3,
                  float* __restrict__ Xprod, int NT) {
  __shared__ __align__(16) char pool[66560];
  short* A3 = (short*)pool;
  char*  B3 = pool + 12288;
  float* C  = (float*)pool;

  const int t = threadIdx.x;
  const int w = t >> 6, lane = t & 63;
  const int l15 = lane & 15, l4 = lane >> 4;
  const int row0 = blockIdx.x * 64;
  const int r = t >> 2, g = t & 3;
  int grow = row0 + r; if (grow >= NT) grow = NT - 1;
  const float* xrow = X + (size_t)grow * DD;

  f32x4 acc[16];
#pragma unroll
  for (int nf = 0; nf < 16; ++nf) { f32x4 z = {0.f, 0.f, 0.f, 0.f}; acc[nf] = z; }

  for (int kit = 0; kit < 8; ++kit) {
    f4 v0 = *(const f4*)(xrow + kit * 32 + g * 8);
    f4 v1 = *(const f4*)(xrow + kit * 32 + g * 8 + 4);
    uint32_t h[8], m[8], l[8];
    split3(v0.x, h[0], m[0], l[0]); split3(v0.y, h[1], m[1], l[1]);
    split3(v0.z, h[2], m[2], l[2]); split3(v0.w, h[3], m[3], l[3]);
    split3(v1.x, h[4], m[4], l[4]); split3(v1.y, h[5], m[5], l[5]);
    split3(v1.z, h[6], m[6], l[6]); split3(v1.w, h[7], m[7], l[7]);
    int slot = (r & 15) + 16 * g;
    int wb = r >> 4;
    *(uint4*)((char*)A3 + ((wb * 3 + 0) * 64 + slot) * 16) =
        make_uint4(h[0] | (h[1] << 16), h[2] | (h[3] << 16), h[4] | (h[5] << 16), h[6] | (h[7] << 16));
    *(uint4*)((char*)A3 + ((wb * 3 + 1) * 64 + slot) * 16) =
        make_uint4(m[0] | (m[1] << 16), m[2] | (m[3] << 16), m[4] | (m[5] << 16), m[6] | (m[7] << 16));
    *(uint4*)((char*)A3 + ((wb * 3 + 2) * 64 + slot) * 16) =
        make_uint4(l[0] | (l[1] << 16), l[2] | (l[3] << 16), l[4] | (l[5] << 16), l[6] | (l[7] << 16));
    const uint4* src = MT3 + (size_t)kit * 3072;
#pragma unroll
    for (int i = 0; i < 12; ++i) {
      int gs = (w * 12 + i) * 64;
      gload_lds16(src + gs + lane, B3 + (size_t)gs * 16);
    }
    __syncthreads();
    bfrag ah = *(const bfrag*)((const char*)A3 + ((w * 3 + 0) * 64 + lane) * 16);
    bfrag am = *(const bfrag*)((const char*)A3 + ((w * 3 + 1) * 64 + lane) * 16);
    bfrag al = *(const bfrag*)((const char*)A3 + ((w * 3 + 2) * 64 + lane) * 16);
#pragma unroll
    for (int nf = 0; nf < 16; ++nf) {
      bfrag bh = *(const bfrag*)(B3 + ((nf * 3 + 0) * 64 + lane) * 16);
      bfrag bm = *(const bfrag*)(B3 + ((nf * 3 + 1) * 64 + lane) * 16);
      bfrag bl = *(const bfrag*)(B3 + ((nf * 3 + 2) * 64 + lane) * 16);
      acc[nf] = __builtin_amdgcn_mfma_f32_16x16x32_bf16(ah, bh, acc[nf], 0, 0, 0);
      acc[nf] = __builtin_amdgcn_mfma_f32_16x16x32_bf16(ah, bm, acc[nf], 0, 0, 0);
      acc[nf] = __builtin_amdgcn_mfma_f32_16x16x32_bf16(am, bh, acc[nf], 0, 0, 0);
      acc[nf] = __builtin_amdgcn_mfma_f32_16x16x32_bf16(ah, bl, acc[nf], 0, 0, 0);
      acc[nf] = __builtin_amdgcn_mfma_f32_16x16x32_bf16(al, bh, acc[nf], 0, 0, 0);
      acc[nf] = __builtin_amdgcn_mfma_f32_16x16x32_bf16(am, bm, acc[nf], 0, 0, 0);
    }
    __syncthreads();
  }
#pragma unroll
  for (int nf = 0; nf < 16; ++nf)
#pragma unroll
    for (int reg = 0; reg < 4; ++reg)
      C[(size_t)(16 * w + l4 * 4 + reg) * 260 + nf * 16 + l15] = acc[nf][reg];
  __syncthreads();
  float part = 0.f;
#pragma unroll
  for (int j = 0; j < 16; ++j) {
    f4 xv = *(const f4*)(xrow + g * 64 + 4 * j);
    f4 cv = *(const f4*)&C[(size_t)r * 260 + g * 64 + 4 * j];
    part = fmaf(xv.x, cv.x, fmaf(xv.y, cv.y, fmaf(xv.z, cv.z, fmaf(xv.w, cv.w, part))));
  }
  part += __shfl_xor(part, 1);
  part += __shfl_xor(part, 2);
  if (g == 0 && row0 + r < NT) Xprod[row0 + r] = part;
}

// ------- cross v11: KS=32 phases, 3 blocks/CU, counted vmcnt(4) -------
__global__ __launch_bounds__(256, 3)
void cross_topk_kernel(const uint4* __restrict__ Xsp, const uint4* __restrict__ Z2h,
                       const float* __restrict__ Xprod,
                       float* __restrict__ cand_v, int* __restrict__ cand_i,
                       int NT, int NCH) {
  __shared__ __align__(16) char Abuf[2][8192];   // [row128][quad-XOR 4x16B]
  __shared__ __align__(16) char Bbuf[2][8192];
  __shared__ __align__(16) float xp_lds[CHUNK];

  const int t = threadIdx.x;
  const int w = t >> 6, lane = t & 63;
  const int l15 = lane & 15, l4 = lane >> 4;
  const int wr = (w & 1) * 64;         // wave row offset
  const int wc = (w >> 1) * 64;        // wave col offset
  // XCD-aware swizzle: same-chunk col-tiles share an XCD's L2
  int n = blockIdx.y * gridDim.x + blockIdx.x;
  int nwg = gridDim.x * gridDim.y;
  int wg = n;
  if ((nwg & 7) == 0) wg = (n & 7) * (nwg >> 3) + (n >> 3);
  const int ct = wg % gridDim.x;
  const int ch = wg / gridDim.x;
  const int c0 = ct * COLS;
  const int row0 = ch * CHUNK;
  const int rows = min(CHUNK, NT - row0);
  const int nrp = (rows + 127) >> 7;
  const int G = nrp * 8;
  const int tile0 = ch * (CHUNK >> 7);

  float bv[4][KNN]; int bi[4][KNN];
#pragma unroll
  for (int nf = 0; nf < 4; ++nf)
#pragma unroll
    for (int s = 0; s < KNN; ++s) { bv[nf][s] = FLT_MAX; bi[nf][s] = 0x7fffffff; }

  f32x4 acc[4][4];
#pragma unroll
  for (int mf = 0; mf < 4; ++mf)
#pragma unroll
    for (int nf = 0; nf < 4; ++nf) { f32x4 z = {0.f, 0.f, 0.f, 0.f}; acc[mf][nf] = z; }

  auto stageA = [&](int gg) {          // one kit32 A tile (512 uint4)
    const uint4* src = Xsp + (((size_t)(tile0 + (gg >> 3)) * 8 + (gg & 7)) << 9);
    char* dst = Abuf[gg & 1];
#pragma unroll
    for (int i = 0; i < 2; ++i) {
      int sb = (w * 2 + i) * 64;
      gload_lds16(src + sb + lane, dst + sb * 16);
    }
  };
  auto stageB = [&](int gg) {
    const uint4* src = Z2h + (size_t)ct * 4096 + ((gg & 7) << 9);
    char* dst = Bbuf[gg & 1];
#pragma unroll
    for (int i = 0; i < 2; ++i) {
      int sb = (w * 2 + i) * 64;
      gload_lds16(src + sb + lane, dst + sb * 16);
    }
  };

  // ---- prologue: Xprod chunk (plain loads -> ds_write), A0/B0 staged ----
  const uint4* xpsrc = (const uint4*)(Xprod + row0);
  for (int i = t; i < CHUNK / 4; i += 256)
    ((uint4*)xp_lds)[i] = xpsrc[i];
  stageA(0); stageB(0);
  __syncthreads();   // drains vmcnt+lgkmcnt, barrier

  for (int rp = 0; rp < nrp; ++rp) {
#pragma unroll
    for (int kit = 0; kit < 8; ++kit) {
      const int g = rp * 8 + kit;
      if (g < G - 1) {
        stageA(g + 1); stageB(g + 1);
        asm volatile("s_waitcnt vmcnt(4)" ::: "memory");
      } else {
        asm volatile("s_waitcnt vmcnt(0)" ::: "memory");
      }
      __builtin_amdgcn_s_barrier();
      const char* Ab = Abuf[kit & 1];
      const char* Bb = Bbuf[kit & 1];
      bfrag ah[4], bh[4];
#pragma unroll
      for (int mf = 0; mf < 4; ++mf) {
        int m = wr + mf * 16 + l15;
        ah[mf] = *(const bfrag*)(Ab + m * 64 + ((l4 ^ (m & 3)) << 4));
      }
#pragma unroll
      for (int nf = 0; nf < 4; ++nf) {
        int cc = wc + nf * 16 + l15;
        bh[nf] = *(const bfrag*)(Bb + cc * 64 + ((l4 ^ (cc & 3)) << 4));
      }
      __builtin_amdgcn_s_setprio(1);
#pragma unroll
      for (int mf = 0; mf < 4; ++mf)
#pragma unroll
        for (int nf = 0; nf < 4; ++nf)
          acc[mf][nf] = __builtin_amdgcn_mfma_f32_16x16x32_bf16(
              ah[mf], bh[nf], acc[mf][nf], 0, 0, 0);
      __builtin_amdgcn_s_setprio(0);
      if (kit == 7) {
        const int trow0 = row0 + rp * 128;
        const bool full = (trow0 + 128 <= NT);
#pragma unroll
        for (int mf = 0; mf < 4; ++mf) {
          f4 xv = *(const f4*)&xp_lds[rp * 128 + wr + mf * 16 + l4 * 4];
          const int rbase = trow0 + wr + mf * 16 + l4 * 4;
#pragma unroll
          for (int nf = 0; nf < 4; ++nf) {
            float v0 = xv.x + acc[mf][nf][0];
            float v1 = xv.y + acc[mf][nf][1];
            float v2 = xv.z + acc[mf][nf][2];
            float v3 = xv.w + acc[mf][nf][3];
            if (!full) {
              if (rbase + 0 >= NT) v0 = FLT_MAX;
              if (rbase + 1 >= NT) v1 = FLT_MAX;
              if (rbase + 2 >= NT) v2 = FLT_MAX;
              if (rbase + 3 >= NT) v3 = FLT_MAX;
            }
            float mn = fminf(fminf(v0, v1), fminf(v2, v3));
            if (mn < bv[nf][4]) {        // rare path: detailed insert
              ins5run(bv[nf], bi[nf], v0, rbase);
              ins5run(bv[nf], bi[nf], v1, rbase + 1);
              ins5run(bv[nf], bi[nf], v2, rbase + 2);
              ins5run(bv[nf], bi[nf], v3, rbase + 3);
            }
            f32x4 zz = {0.f, 0.f, 0.f, 0.f};
            acc[mf][nf] = zz;
          }
        }
      }
      __builtin_amdgcn_s_barrier();
    }
  }

  // write 8 partial lists per column, layout [col][ch][src][5]
#pragma unroll
  for (int nf = 0; nf < 4; ++nf) {
    int col = c0 + wc + nf * 16 + l15;
    size_t o = ((size_t)col * NCH + ch) * (NSRC * KNN) + ((w & 1) * 4 + l4) * KNN;
#pragma unroll
    for (int s = 0; s < KNN; ++s) { cand_v[o + s] = bv[nf][s]; cand_i[o + s] = bi[nf][s]; }
  }
}

// ------------- finalize: merge -> top-10 -> exact rescore -> top-5 -------------
__global__ __launch_bounds__(64)
void finalize_kernel(const float* __restrict__ cand_v, const int* __restrict__ cand_i,
                     const float* __restrict__ X, const float* __restrict__ ZTf32,
                     const float* __restrict__ Xprod, const int* __restrict__ y,
                     float* __restrict__ out, int NCH, int NEVAL, int NT) {
  __shared__ float ztl[DD];
  const int j = blockIdx.x;
  const int lane = threadIdx.x;
#pragma unroll
  for (int i = 0; i < 4; ++i) {
    int k = lane + 64 * i;
    ztl[k] = ZTf32[(size_t)k * NEVAL + j];
  }
  __syncthreads();

  float bv[10]; int bi[10];
#pragma unroll
  for (int s = 0; s < 10; ++s) { bv[s] = FLT_MAX; bi[s] = 0x7fffffff; }
  const int NC = NCH * NSRC * KNN;     // contiguous per column
  const float* cvj = cand_v + (size_t)j * NC;
  const int*   cij = cand_i + (size_t)j * NC;
  for (int p = lane; p < NC; p += 64)
    ins10(bv, bi, cvj[p], cij[p]);
#pragma unroll
  for (int st = 0; st < 6; ++st) {
    float pv[10]; int pi[10];
#pragma unroll
    for (int s = 0; s < 10; ++s) {
      pv[s] = __shfl_xor(bv[s], 1 << st);
      pi[s] = __shfl_xor(bi[s], 1 << st);
    }
#pragma unroll
    for (int s = 0; s < 10; ++s) ins10(bv, bi, pv[s], pi[s]);
  }
  float ex[10];
#pragma unroll
  for (int c = 0; c < 10; ++c) {
    int idx = bi[c];
    float part = 0.f;
#pragma unroll
    for (int i = 0; i < 4; ++i) {
      int k = lane + 64 * i;
      part = fmaf(X[(size_t)idx * DD + k], ztl[k], part);
    }
#pragma unroll
    for (int st = 0; st < 6; ++st) part += __shfl_xor(part, 1 << st);
    ex[c] = Xprod[idx] - 2.f * part;
  }
  float fv[KNN]; int fi[KNN];
#pragma unroll
  for (int s = 0; s < KNN; ++s) { fv[s] = FLT_MAX; fi[s] = 0x7fffffff; }
#pragma unroll
  for (int c = 0; c < 10; ++c) ins5lex(fv, fi, ex[c], bi[c]);
  int lb[KNN];
#pragma unroll
  for (int s = 0; s < KNN; ++s) lb[s] = y[fi[s]];
  for (int q = lane; q < NLAB; q += 64) {
    int cnt = (lb[0] == q) + (lb[1] == q) + (lb[2] == q) + (lb[3] == q) + (lb[4] == q);
    out[(size_t)j * NLAB + q] = (float)cnt - (float)q * 0.01f;
  }
}

extern "C" void kernel_launch(void* const* d_in, const int* in_sizes, int n_in,
                              void* d_out, int out_size, void* d_ws, size_t ws_size,
                              hipStream_t stream) {
  const float* X  = (const float*)d_in[0];
  const float* M  = (const float*)d_in[1];
  const float* Xe = (const float*)d_in[2];
  const int*   y  = (const int*)d_in[3];
  const int NT    = in_sizes[0] / DD;          // 100000
  const int NEVAL = in_sizes[2] / DD;          // 2048
  const int NCH   = (NT + CHUNK - 1) / CHUNK;  // 46
  const int NT64  = (NT + 63) / 64;
  const int NT128 = (NT + 127) / 128;          // 782

  char* ws = (char*)d_ws;
  uint4* Z2h    = (uint4*)ws;                               // 1 MB
  float* ZTf32  = (float*)(ws + (1 << 20));                 // 2 MB
  uint4* MT3    = (uint4*)(ws + (3 << 20));                 // 384 KB
  float* Xprod  = (float*)(ws + (3 << 20) + (448 << 10));   // NCH*CHUNK + pad
  float* cand_v = (float*)(ws + (4 << 20));                 // 15.1 MB
  int*   cand_i = (int*)(cand_v + (size_t)NEVAL * NCH * NSRC * KNN);
  uint4* Xsp    = (uint4*)(ws + (40ULL << 20));             // 51.2 MB
  float* out    = (float*)d_out;

  const int NTOT = NT128 * 4096;               // Xsp uint4 count

  msplit_kernel<<<dim3(32), 256, 0, stream>>>(M, MT3);
  prep_kernel<<<dim3(NEVAL / 64, DD / 64), 256, 0, stream>>>(M, Xe, ZTf32, Z2h, NEVAL);
  xsplit_kernel<<<dim3((NTOT + 255) / 256), 256, 0, stream>>>(X, Xsp, NT, NTOT);
  xprod_kernel<<<dim3(NT64), 256, 0, stream>>>(X, MT3, Xprod, NT);
  cross_topk_kernel<<<dim3(NEVAL / COLS, NCH), 256, 0, stream>>>(
      Xsp, Z2h, Xprod, cand_v, cand_i, NT, NCH);
  finalize_kernel<<<dim3(NEVAL), 64, 0, stream>>>(
      cand_v, cand_i, X, ZTf32, Xprod, y, out, NCH, NEVAL, NT);
}

// Round 12
// 399.768 us; speedup vs baseline: 1.6399x; 1.3031x over previous
//
#include <hip/hip_runtime.h>
#include <cfloat>
#include <cstdint>

// MahalanobisKnnModule v12: v8's proven layout/protocol at 3 blocks/CU.
//   R11 lessons: 64B-row quad-XOR conflicts (keep 128B-row oct-XOR);
//   launch_bounds(256,3) caps regs at ~170 -> acc must shrink to [4][2].
//   cross: block 128 rows x 64 cols (4 waves 2x2, wave 64x32), KS=64,
//   A dbuf 32KB + B dbuf 16KB + xp slice 1KB = 48.5KB -> 3 blocks/CU;
//   grid 32x24 = 768 = exactly 3/CU, one round; counted vmcnt(3).
//   xp staged per rowpair-pair via gload_lds (drains inside the counted
//   pipeline; no vmcnt(0) pollution).
//   msplit/xsplit/xprod/finalize: v8 versions (ref-verified absmax 0);
//   prep re-indexed for 64-col B tiles.

#define DD    256
#define NLAB  100
#define KNN   5
#define BCOLS 64
#define CHUNK 4224
#define NSRC  8

typedef float4 f4;
typedef __attribute__((ext_vector_type(8))) short bfrag;   // 8 bf16
typedef __attribute__((ext_vector_type(4))) float f32x4;

__device__ __forceinline__ void gload_lds16(const void* g, void* l) {
  __builtin_amdgcn_global_load_lds(
      (const __attribute__((address_space(1))) void*)g,
      (__attribute__((address_space(3))) void*)l, 16, 0, 0);
}

__device__ __forceinline__ uint32_t hi16(float v) {
  return ((__float_as_uint(v) + 0x8000u) & 0xffff0000u) >> 16;
}

__device__ __forceinline__ void split3(float v, uint32_t& h, uint32_t& m, uint32_t& l) {
  uint32_t b = __float_as_uint(v);
  uint32_t hb = (b + 0x8000u) & 0xffff0000u;
  float r1 = v - __uint_as_float(hb);
  uint32_t b1 = __float_as_uint(r1);
  uint32_t mb = (b1 + 0x8000u) & 0xffff0000u;
  float r2 = r1 - __uint_as_float(mb);
  uint32_t lb = (__float_as_uint(r2) + 0x8000u) & 0xffff0000u;
  h = hb >> 16; m = mb >> 16; l = lb >> 16;
}

__device__ __forceinline__ bool lex_lt(float v, int id, float rv, int rid) {
  return (v < rv) || (v == rv && id < rid);
}

__device__ __forceinline__ void ins5run(float (&bv)[KNN], int (&bi)[KNN], float v, int id) {
  if (v < bv[4]) {
    if (v < bv[3]) {
      bv[4] = bv[3]; bi[4] = bi[3];
      if (v < bv[2]) {
        bv[3] = bv[2]; bi[3] = bi[2];
        if (v < bv[1]) {
          bv[2] = bv[1]; bi[2] = bi[1];
          if (v < bv[0]) {
            bv[1] = bv[0]; bi[1] = bi[0]; bv[0] = v; bi[0] = id;
          } else { bv[1] = v; bi[1] = id; }
        } else { bv[2] = v; bi[2] = id; }
      } else { bv[3] = v; bi[3] = id; }
    } else { bv[4] = v; bi[4] = id; }
  }
}

__device__ __forceinline__ void ins5lex(float (&bv)[KNN], int (&bi)[KNN], float v, int id) {
  if (!lex_lt(v, id, bv[4], bi[4])) return;
  if (lex_lt(v, id, bv[3], bi[3])) {
    bv[4] = bv[3]; bi[4] = bi[3];
    if (lex_lt(v, id, bv[2], bi[2])) {
      bv[3] = bv[2]; bi[3] = bi[2];
      if (lex_lt(v, id, bv[1], bi[1])) {
        bv[2] = bv[1]; bi[2] = bi[1];
        if (lex_lt(v, id, bv[0], bi[0])) {
          bv[1] = bv[0]; bi[1] = bi[0]; bv[0] = v; bi[0] = id;
        } else { bv[1] = v; bi[1] = id; }
      } else { bv[2] = v; bi[2] = id; }
    } else { bv[3] = v; bi[3] = id; }
  } else { bv[4] = v; bi[4] = id; }
}

__device__ __forceinline__ void ins10(float (&bv)[10], int (&bi)[10], float v, int id) {
  if (!lex_lt(v, id, bv[9], bi[9])) return;
  bool placed = false;
#pragma unroll
  for (int s = 9; s >= 1; --s) {
    if (!placed) {
      if (lex_lt(v, id, bv[s - 1], bi[s - 1])) { bv[s] = bv[s - 1]; bi[s] = bi[s - 1]; }
      else { bv[s] = v; bi[s] = id; placed = true; }
    }
  }
  if (!placed) { bv[0] = v; bi[0] = id; }
}

// ---------- msplit: MT3 = 3-split of M, frag order for xprod ----------
__global__ __launch_bounds__(256)
void msplit_kernel(const float* __restrict__ M, uint4* __restrict__ MT3) {
  int id = blockIdx.x * 256 + threadIdx.x;
  int lane = id & 63;
  int nf = (id >> 6) & 15;
  int kit = id >> 10;
  int d = nf * 16 + (lane & 15);
  int kb = kit * 32 + (lane >> 4) * 8;
  uint32_t hw[4], mw[4], lw[4];
#pragma unroll
  for (int e = 0; e < 4; ++e) {
    uint32_t h0, m0, l0, h1, m1, l1;
    split3(M[(size_t)(kb + 2 * e) * DD + d], h0, m0, l0);
    split3(M[(size_t)(kb + 2 * e + 1) * DD + d], h1, m1, l1);
    hw[e] = h0 | (h1 << 16); mw[e] = m0 | (m1 << 16); lw[e] = l0 | (l1 << 16);
  }
  size_t base = (size_t)(kit * 16 + nf) * 3 * 64;
  MT3[base + lane]       = make_uint4(hw[0], hw[1], hw[2], hw[3]);
  MT3[base + 64 + lane]  = make_uint4(mw[0], mw[1], mw[2], mw[3]);
  MT3[base + 128 + lane] = make_uint4(lw[0], lw[1], lw[2], lw[3]);
}

// ---------- xsplit (v8): Xsp[tile128][kit64][1024 slots], oct-XOR ----------
// slot s: row m = s>>3, pos = s&7, k-oct jj = pos ^ (m&7); holds hi bf16 of
// X[row][kit64*64 + jj*8 .. +7]. 128B per row.
__global__ __launch_bounds__(256)
void xsplit_kernel(const float* __restrict__ X, uint4* __restrict__ Xsp,
                   int NT, int NT128) {
  int id = blockIdx.x * 256 + threadIdx.x;
  int tile = id >> 12;
  if (tile >= NT128) return;
  int rem = id & 4095;
  int kit = rem >> 10;
  int s = rem & 1023;
  int m = s >> 3, pos = s & 7;
  int jj = pos ^ (m & 7);
  int row = tile * 128 + m; if (row >= NT) row = NT - 1;
  const float* src = X + (size_t)row * DD + kit * 64 + jj * 8;
  f4 v0 = *(const f4*)src;
  f4 v1 = *(const f4*)(src + 4);
  uint32_t h0 = hi16(v0.x) | (hi16(v0.y) << 16);
  uint32_t h1 = hi16(v0.z) | (hi16(v0.w) << 16);
  uint32_t h2 = hi16(v1.x) | (hi16(v1.y) << 16);
  uint32_t h3 = hi16(v1.z) | (hi16(v1.w) << 16);
  Xsp[(((size_t)tile * 4 + kit) << 10) + s] = make_uint4(h0, h1, h2, h3);
}

// ---------- prep: ZTf32 + Z2h[ct64][kit64][cc*8 + (jj^(cc&7))] ----------
__global__ __launch_bounds__(256)
void prep_kernel(const float* __restrict__ M, const float* __restrict__ Xe,
                 float* __restrict__ ZTf32, uint4* __restrict__ Z2h, int NEVAL) {
  __shared__ float xe_lds[64 * 257];
  const int t = threadIdx.x;
  const int j0 = blockIdx.x * 64;
  const int part = t >> 6;
  const int dbase = blockIdx.y * 64 + part * 16;
#pragma unroll
  for (int it = 0; it < 16; ++it) {
    int id = t + it * 256;
    int r = id >> 6, k4 = id & 63;
    f4 v = *(const f4*)(Xe + (size_t)(j0 + r) * DD + 4 * k4);
    float* p = &xe_lds[r * 257 + 4 * k4];
    p[0] = v.x; p[1] = v.y; p[2] = v.z; p[3] = v.w;
  }
  __syncthreads();
  const int j = t & 63;
  float acc[16];
#pragma unroll
  for (int dd = 0; dd < 16; ++dd) acc[dd] = 0.f;
  for (int k4 = 0; k4 < 64; ++k4) {
    const float* xp = &xe_lds[j * 257 + 4 * k4];
    float x0 = xp[0], x1 = xp[1], x2 = xp[2], x3 = xp[3];
#pragma unroll
    for (int dd = 0; dd < 16; ++dd) {
      f4 m = *(const f4*)(M + (size_t)(dbase + dd) * DD + 4 * k4);
      acc[dd] = fmaf(m.x, x0, fmaf(m.y, x1, fmaf(m.z, x2, fmaf(m.w, x3, acc[dd]))));
    }
  }
  const int jg = j0 + j;
#pragma unroll
  for (int dd = 0; dd < 16; ++dd)
    ZTf32[(size_t)(dbase + dd) * NEVAL + jg] = acc[dd];
  const int cc = jg & 63, ct2 = jg >> 6;        // 64-col tiles now
  const int kit64 = dbase >> 6;
  const int jb = (dbase & 63) >> 3;             // {0,2,4,6}
  size_t zbase = (size_t)ct2 * 2048 + kit64 * 512 + cc * 8;
#pragma unroll
  for (int u = 0; u < 2; ++u) {
    int jj = jb + u;
    uint32_t hw[4];
#pragma unroll
    for (int e = 0; e < 4; ++e) {
      uint32_t a0 = hi16(-2.f * acc[u * 8 + 2 * e]);
      uint32_t a1 = hi16(-2.f * acc[u * 8 + 2 * e + 1]);
      hw[e] = a0 | (a1 << 16);
    }
    Z2h[zbase + (jj ^ (cc & 7))] = make_uint4(hw[0], hw[1], hw[2], hw[3]);
  }
}

// ---------- xprod: 3-split MFMA GEMM + fused row-dot (unchanged) ----------
__global__ __launch_bounds__(256, 2)
void xprod_kernel(const float* __restrict__ X, const uint4* __restrict__ MT3,
                  float* __restrict__ Xprod, int NT) {
  __shared__ __align__(16) char pool[66560];
  short* A3 = (short*)pool;
  char*  B3 = pool + 12288;
  float* C  = (float*)pool;

  const int t = threadIdx.x;
  const int w = t >> 6, lane = t & 63;
  const int l15 = lane & 15, l4 = lane >> 4;
  const int row0 = blockIdx.x * 64;
  const int r = t >> 2, g = t & 3;
  int grow = row0 + r; if (grow >= NT) grow = NT - 1;
  const float* xrow = X + (size_t)grow * DD;

  f32x4 acc[16];
#pragma unroll
  for (int nf = 0; nf < 16; ++nf) { f32x4 z = {0.f, 0.f, 0.f, 0.f}; acc[nf] = z; }

  for (int kit = 0; kit < 8; ++kit) {
    f4 v0 = *(const f4*)(xrow + kit * 32 + g * 8);
    f4 v1 = *(const f4*)(xrow + kit * 32 + g * 8 + 4);
    uint32_t h[8], m[8], l[8];
    split3(v0.x, h[0], m[0], l[0]); split3(v0.y, h[1], m[1], l[1]);
    split3(v0.z, h[2], m[2], l[2]); split3(v0.w, h[3], m[3], l[3]);
    split3(v1.x, h[4], m[4], l[4]); split3(v1.y, h[5], m[5], l[5]);
    split3(v1.z, h[6], m[6], l[6]); split3(v1.w, h[7], m[7], l[7]);
    int slot = (r & 15) + 16 * g;
    int wb = r >> 4;
    *(uint4*)((char*)A3 + ((wb * 3 + 0) * 64 + slot) * 16) =
        make_uint4(h[0] | (h[1] << 16), h[2] | (h[3] << 16), h[4] | (h[5] << 16), h[6] | (h[7] << 16));
    *(uint4*)((char*)A3 + ((wb * 3 + 1) * 64 + slot) * 16) =
        make_uint4(m[0] | (m[1] << 16), m[2] | (m[3] << 16), m[4] | (m[5] << 16), m[6] | (m[7] << 16));
    *(uint4*)((char*)A3 + ((wb * 3 + 2) * 64 + slot) * 16) =
        make_uint4(l[0] | (l[1] << 16), l[2] | (l[3] << 16), l[4] | (l[5] << 16), l[6] | (l[7] << 16));
    const uint4* src = MT3 + (size_t)kit * 3072;
#pragma unroll
    for (int i = 0; i < 12; ++i) {
      int gs = (w * 12 + i) * 64;
      gload_lds16(src + gs + lane, B3 + (size_t)gs * 16);
    }
    __syncthreads();
    bfrag ah = *(const bfrag*)((const char*)A3 + ((w * 3 + 0) * 64 + lane) * 16);
    bfrag am = *(const bfrag*)((const char*)A3 + ((w * 3 + 1) * 64 + lane) * 16);
    bfrag al = *(const bfrag*)((const char*)A3 + ((w * 3 + 2) * 64 + lane) * 16);
#pragma unroll
    for (int nf = 0; nf < 16; ++nf) {
      bfrag bh = *(const bfrag*)(B3 + ((nf * 3 + 0) * 64 + lane) * 16);
      bfrag bm = *(const bfrag*)(B3 + ((nf * 3 + 1) * 64 + lane) * 16);
      bfrag bl = *(const bfrag*)(B3 + ((nf * 3 + 2) * 64 + lane) * 16);
      acc[nf] = __builtin_amdgcn_mfma_f32_16x16x32_bf16(ah, bh, acc[nf], 0, 0, 0);
      acc[nf] = __builtin_amdgcn_mfma_f32_16x16x32_bf16(ah, bm, acc[nf], 0, 0, 0);
      acc[nf] = __builtin_amdgcn_mfma_f32_16x16x32_bf16(am, bh, acc[nf], 0, 0, 0);
      acc[nf] = __builtin_amdgcn_mfma_f32_16x16x32_bf16(ah, bl, acc[nf], 0, 0, 0);
      acc[nf] = __builtin_amdgcn_mfma_f32_16x16x32_bf16(al, bh, acc[nf], 0, 0, 0);
      acc[nf] = __builtin_amdgcn_mfma_f32_16x16x32_bf16(am, bm, acc[nf], 0, 0, 0);
    }
    __syncthreads();
  }
#pragma unroll
  for (int nf = 0; nf < 16; ++nf)
#pragma unroll
    for (int reg = 0; reg < 4; ++reg)
      C[(size_t)(16 * w + l4 * 4 + reg) * 260 + nf * 16 + l15] = acc[nf][reg];
  __syncthreads();
  float part = 0.f;
#pragma unroll
  for (int j = 0; j < 16; ++j) {
    f4 xv = *(const f4*)(xrow + g * 64 + 4 * j);
    f4 cv = *(const f4*)&C[(size_t)r * 260 + g * 64 + 4 * j];
    part = fmaf(xv.x, cv.x, fmaf(xv.y, cv.y, fmaf(xv.z, cv.z, fmaf(xv.w, cv.w, part))));
  }
  part += __shfl_xor(part, 1);
  part += __shfl_xor(part, 2);
  if (g == 0 && row0 + r < NT) Xprod[row0 + r] = part;
}

// ------- cross v12: 128x64 tile, 3 blocks/CU, v8 layout + vmcnt(3) -------
__global__ __launch_bounds__(256, 3)
void cross_topk_kernel(const uint4* __restrict__ Xsp, const uint4* __restrict__ Z2h,
                       const float* __restrict__ Xprod,
                       float* __restrict__ cand_v, int* __restrict__ cand_i,
                       int NT, int NCH, int NT128) {
  __shared__ __align__(16) char Abuf[2][16384];   // [row128][128B oct-XOR]
  __shared__ __align__(16) char Bbuf[2][8192];    // [col64][128B oct-XOR]
  __shared__ __align__(16) float xp_lds[256];     // 2 rowpairs of Xprod

  const int t = threadIdx.x;
  const int w = t >> 6, lane = t & 63;
  const int l15 = lane & 15, l4 = lane >> 4;
  const int wr = (w & 1) * 64;         // wave row offset
  const int wc = (w >> 1) * 32;        // wave col offset
  // XCD-aware swizzle
  int n = blockIdx.y * gridDim.x + blockIdx.x;
  int nwg = gridDim.x * gridDim.y;
  int wg = n;
  if ((nwg & 7) == 0) wg = (n & 7) * (nwg >> 3) + (n >> 3);
  const int ct = wg % gridDim.x;
  const int ch = wg / gridDim.x;
  const int c0 = ct * BCOLS;
  const int row0 = ch * CHUNK;
  const int rows = min(CHUNK, NT - row0);
  const int nrp = (rows + 127) >> 7;
  const int G = nrp * 4;
  const int tile0 = ch * (CHUNK >> 7);

  float bv[2][KNN]; int bi[2][KNN];
#pragma unroll
  for (int nf = 0; nf < 2; ++nf)
#pragma unroll
    for (int s = 0; s < KNN; ++s) { bv[nf][s] = FLT_MAX; bi[nf][s] = 0x7fffffff; }

  f32x4 acc[4][2];
#pragma unroll
  for (int mf = 0; mf < 4; ++mf)
#pragma unroll
    for (int nf = 0; nf < 2; ++nf) { f32x4 z = {0.f, 0.f, 0.f, 0.f}; acc[mf][nf] = z; }

  auto stageA = [&](int gg) {          // one kit64 A tile (1024 uint4)
    int tile = tile0 + (gg >> 2); if (tile >= NT128) tile = NT128 - 1;
    const uint4* src = Xsp + (((size_t)tile * 4 + (gg & 3)) << 10);
    char* dst = Abuf[gg & 1];
#pragma unroll
    for (int i = 0; i < 4; ++i) {
      int sb = (w * 4 + i) * 64;
      gload_lds16(src + sb + lane, dst + sb * 16);
    }
  };
  auto stageB = [&](int gg) {          // one kit64 B tile (512 uint4)
    const uint4* src = Z2h + (size_t)ct * 2048 + (gg & 3) * 512;
    char* dst = Bbuf[gg & 1];
#pragma unroll
    for (int i = 0; i < 2; ++i) {
      int sb = (w * 2 + i) * 64;
      gload_lds16(src + sb + lane, dst + sb * 16);
    }
  };

  // prologue: A0/B0 staged, full drain, single barrier
  stageA(0); stageB(0);
  asm volatile("s_waitcnt vmcnt(0)" ::: "memory");
  __builtin_amdgcn_s_barrier();

  for (int rp = 0; rp < nrp; ++rp) {
#pragma unroll
    for (int kit = 0; kit < 4; ++kit) {
      const int g = rp * 4 + kit;
      if (g < G - 1) {
        stageA(g + 1); stageB(g + 1);
        if (kit == 0 && !(rp & 1)) {
          // xp slice for rowpairs rp, rp+1 (1KB); all waves issue the same
          // load (benign duplicate) -> symmetric per-wave vmcnt accounting.
          // Drained by the next phase's vmcnt(3)+barrier, read at kit==3.
          gload_lds16((const uint4*)(Xprod + row0 + rp * 128) + lane,
                      (char*)xp_lds);
        }
        asm volatile("s_waitcnt vmcnt(3)" ::: "memory");
      } else {
        asm volatile("s_waitcnt vmcnt(0)" ::: "memory");
      }
      __builtin_amdgcn_s_barrier();
      const char* Ab = Abuf[kit & 1];
      const char* Bb = Bbuf[kit & 1];
      bfrag ah[4][2], bh[2][2];
#pragma unroll
      for (int mf = 0; mf < 4; ++mf) {
        int m = wr + mf * 16 + l15;
        const char* rb = Ab + m * 128;
#pragma unroll
        for (int ks = 0; ks < 2; ++ks)
          ah[mf][ks] = *(const bfrag*)(rb + (((ks * 4 + l4) ^ (m & 7)) << 4));
      }
#pragma unroll
      for (int nf = 0; nf < 2; ++nf) {
        int cc = wc + nf * 16 + l15;
        const char* rb = Bb + cc * 128;
#pragma unroll
        for (int ks = 0; ks < 2; ++ks)
          bh[nf][ks] = *(const bfrag*)(rb + (((ks * 4 + l4) ^ (cc & 7)) << 4));
      }
      __builtin_amdgcn_s_setprio(1);
#pragma unroll
      for (int ks = 0; ks < 2; ++ks)
#pragma unroll
        for (int mf = 0; mf < 4; ++mf)
#pragma unroll
          for (int nf = 0; nf < 2; ++nf)
            acc[mf][nf] = __builtin_amdgcn_mfma_f32_16x16x32_bf16(
                ah[mf][ks], bh[nf][ks], acc[mf][nf], 0, 0, 0);
      __builtin_amdgcn_s_setprio(0);
      if (kit == 3) {
        const int trow0 = row0 + rp * 128;
        const bool full = (trow0 + 128 <= NT);
#pragma unroll
        for (int mf = 0; mf < 4; ++mf) {
          f4 xv = *(const f4*)&xp_lds[(rp & 1) * 128 + wr + mf * 16 + l4 * 4];
          const int rbase = trow0 + wr + mf * 16 + l4 * 4;
#pragma unroll
          for (int nf = 0; nf < 2; ++nf) {
            float v0 = xv.x + acc[mf][nf][0];
            float v1 = xv.y + acc[mf][nf][1];
            float v2 = xv.z + acc[mf][nf][2];
            float v3 = xv.w + acc[mf][nf][3];
            if (!full) {
              if (rbase + 0 >= NT) v0 = FLT_MAX;
              if (rbase + 1 >= NT) v1 = FLT_MAX;
              if (rbase + 2 >= NT) v2 = FLT_MAX;
              if (rbase + 3 >= NT) v3 = FLT_MAX;
            }
            float mn = fminf(fminf(v0, v1), fminf(v2, v3));
            if (mn < bv[nf][4]) {        // rare path: detailed insert
              ins5run(bv[nf], bi[nf], v0, rbase);
              ins5run(bv[nf], bi[nf], v1, rbase + 1);
              ins5run(bv[nf], bi[nf], v2, rbase + 2);
              ins5run(bv[nf], bi[nf], v3, rbase + 3);
            }
            f32x4 zz = {0.f, 0.f, 0.f, 0.f};
            acc[mf][nf] = zz;
          }
        }
      }
      __builtin_amdgcn_s_barrier();
    }
  }

  // write 8 partial lists per column, layout [col][ch][src][5]
#pragma unroll
  for (int nf = 0; nf < 2; ++nf) {
    int col = c0 + wc + nf * 16 + l15;
    size_t o = ((size_t)col * NCH + ch) * (NSRC * KNN) + ((w & 1) * 4 + l4) * KNN;
#pragma unroll
    for (int s = 0; s < KNN; ++s) { cand_v[o + s] = bv[nf][s]; cand_i[o + s] = bi[nf][s]; }
  }
}

// ------------- finalize: merge -> top-10 -> exact rescore -> top-5 -------------
__global__ __launch_bounds__(64)
void finalize_kernel(const float* __restrict__ cand_v, const int* __restrict__ cand_i,
                     const float* __restrict__ X, const float* __restrict__ ZTf32,
                     const float* __restrict__ Xprod, const int* __restrict__ y,
                     float* __restrict__ out, int NCH, int NEVAL, int NT) {
  __shared__ float ztl[DD];
  const int j = blockIdx.x;
  const int lane = threadIdx.x;
#pragma unroll
  for (int i = 0; i < 4; ++i) {
    int k = lane + 64 * i;
    ztl[k] = ZTf32[(size_t)k * NEVAL + j];
  }
  __syncthreads();

  float bv[10]; int bi[10];
#pragma unroll
  for (int s = 0; s < 10; ++s) { bv[s] = FLT_MAX; bi[s] = 0x7fffffff; }
  const int NC = NCH * NSRC * KNN;     // 960, contiguous per column
  const float* cvj = cand_v + (size_t)j * NC;
  const int*   cij = cand_i + (size_t)j * NC;
  for (int p = lane; p < NC; p += 64)
    ins10(bv, bi, cvj[p], cij[p]);
#pragma unroll
  for (int st = 0; st < 6; ++st) {
    float pv[10]; int pi[10];
#pragma unroll
    for (int s = 0; s < 10; ++s) {
      pv[s] = __shfl_xor(bv[s], 1 << st);
      pi[s] = __shfl_xor(bi[s], 1 << st);
    }
#pragma unroll
    for (int s = 0; s < 10; ++s) ins10(bv, bi, pv[s], pi[s]);
  }
  float ex[10];
#pragma unroll
  for (int c = 0; c < 10; ++c) {
    int idx = bi[c];
    float part = 0.f;
#pragma unroll
    for (int i = 0; i < 4; ++i) {
      int k = lane + 64 * i;
      part = fmaf(X[(size_t)idx * DD + k], ztl[k], part);
    }
#pragma unroll
    for (int st = 0; st < 6; ++st) part += __shfl_xor(part, 1 << st);
    ex[c] = Xprod[idx] - 2.f * part;
  }
  float fv[KNN]; int fi[KNN];
#pragma unroll
  for (int s = 0; s < KNN; ++s) { fv[s] = FLT_MAX; fi[s] = 0x7fffffff; }
#pragma unroll
  for (int c = 0; c < 10; ++c) ins5lex(fv, fi, ex[c], bi[c]);
  int lb[KNN];
#pragma unroll
  for (int s = 0; s < KNN; ++s) lb[s] = y[fi[s]];
  for (int q = lane; q < NLAB; q += 64) {
    int cnt = (lb[0] == q) + (lb[1] == q) + (lb[2] == q) + (lb[3] == q) + (lb[4] == q);
    out[(size_t)j * NLAB + q] = (float)cnt - (float)q * 0.01f;
  }
}

extern "C" void kernel_launch(void* const* d_in, const int* in_sizes, int n_in,
                              void* d_out, int out_size, void* d_ws, size_t ws_size,
                              hipStream_t stream) {
  const float* X  = (const float*)d_in[0];
  const float* M  = (const float*)d_in[1];
  const float* Xe = (const float*)d_in[2];
  const int*   y  = (const int*)d_in[3];
  const int NT    = in_sizes[0] / DD;          // 100000
  const int NEVAL = in_sizes[2] / DD;          // 2048
  const int NCH   = (NT + CHUNK - 1) / CHUNK;  // 24
  const int NT64  = (NT + 63) / 64;
  const int NT128 = (NT + 127) / 128;          // 782

  char* ws = (char*)d_ws;
  uint4* Z2h    = (uint4*)ws;                               // 1 MB
  float* ZTf32  = (float*)(ws + (1 << 20));                 // 2 MB
  uint4* MT3    = (uint4*)(ws + (3 << 20));                 // 384 KB
  float* Xprod  = (float*)(ws + (3 << 20) + (448 << 10));   // NCH*CHUNK + pad
  float* cand_v = (float*)(ws + (4 << 20));                 // 7.9 MB
  int*   cand_i = (int*)(cand_v + (size_t)NEVAL * NCH * NSRC * KNN);
  uint4* Xsp    = (uint4*)(ws + (40ULL << 20));             // 51.2 MB
  float* out    = (float*)d_out;

  msplit_kernel<<<dim3(32), 256, 0, stream>>>(M, MT3);
  prep_kernel<<<dim3(NEVAL / 64, DD / 64), 256, 0, stream>>>(M, Xe, ZTf32, Z2h, NEVAL);
  xsplit_kernel<<<dim3(NT128 * 16), 256, 0, stream>>>(X, Xsp, NT, NT128);
  xprod_kernel<<<dim3(NT64), 256, 0, stream>>>(X, MT3, Xprod, NT);
  cross_topk_kernel<<<dim3(NEVAL / BCOLS, NCH), 256, 0, stream>>>(
      Xsp, Z2h, Xprod, cand_v, cand_i, NT, NCH, NT128);
  finalize_kernel<<<dim3(NEVAL), 64, 0, stream>>>(
      cand_v, cand_i, X, ZTf32, Xprod, y, out, NCH, NEVAL, NT);
}